// Round 1
// baseline (647.201 us; speedup 1.0000x reference)
//
#include <hip/hip_runtime.h>

// QECC statevector: 23 qubits, DIM = 2^23 amplitudes, N0 = 2 vectors per code.
// Gate ind0 acts on statevector bit p = 22 - ind0:  new_d = sum_b old_b * U[b,d].
#define DIM_ (1 << 23)
#define N0_ 2

// overlap accumulators {R00,I00,R01,I01,R10,I10,R11,I11}; zeroed by k_zero each launch
__device__ float g_acc[8];

// Bank-conflict swizzle, bijective on 13-bit LDS indices:
// bits 0,1 ^= bits 5,6 ; bits 2..4 ^= bits 7..9.
// Chosen so every write/read phase in both kernels spreads 64 lanes over all
// 16 float2-bank-pairs (b64 ops at the 4-cycle optimum, no excess conflicts).
__device__ __forceinline__ int swz(int x) {
    return x ^ ((x >> 5) & 3) ^ (((x >> 7) & 7) << 2);
}

__device__ __forceinline__ void gload(const float* __restrict__ ur,
                                      const float* __restrict__ ui, int q,
                                      float2& u00, float2& u01, float2& u10, float2& u11) {
    u00 = make_float2(ur[q * 4 + 0], ui[q * 4 + 0]);
    u01 = make_float2(ur[q * 4 + 1], ui[q * 4 + 1]);
    u10 = make_float2(ur[q * 4 + 2], ui[q * 4 + 2]);
    u11 = make_float2(ur[q * 4 + 3], ui[q * 4 + 3]);
}

// out0 = u00*a0 + u10*a1 ; out1 = u01*a0 + u11*a1   (complex, per einsum convention)
__device__ __forceinline__ void bfly(float2& a0, float2& a1,
                                     float2 u00, float2 u01, float2 u10, float2 u11) {
    float2 n0, n1;
    n0.x = a0.x * u00.x - a0.y * u00.y + a1.x * u10.x - a1.y * u10.y;
    n0.y = a0.x * u00.y + a0.y * u00.x + a1.x * u10.y + a1.y * u10.x;
    n1.x = a0.x * u01.x - a0.y * u01.y + a1.x * u11.x - a1.y * u11.y;
    n1.y = a0.x * u01.y + a0.y * u01.x + a1.x * u11.y + a1.y * u11.x;
    a0 = n0; a1 = n1;
}

// Butterfly all pairs of the 32-register file v[] differing in bit log2(S), gate q.
#define BFLY_STRIDE(S, Q)                                                      \
    do {                                                                       \
        float2 u00, u01, u10, u11;                                             \
        gload(ur, ui, (Q), u00, u01, u10, u11);                                \
        _Pragma("unroll")                                                      \
        for (int m0 = 0; m0 < 32; ++m0)                                        \
            if (!(m0 & (S))) bfly(v[m0], v[m0 + (S)], u00, u01, u10, u11);     \
    } while (0)

// ---------------------------------------------------------------------------
// K1: low 13 statevector bits (gates q = 22..10). One block = one contiguous
// 8192-complex chunk. 256 thr x 32 complex in registers; 3 register phases:
//   A: bits {0,1,10,11,12}   (from the float4 load layout)
//   B: bits {2..6}           (after LDS remap)
//   C: bits {7,8,9}          (after LDS remap)
// then a final LDS remap to a linear layout for perfectly coalesced stores.
// ---------------------------------------------------------------------------
template <bool INTER>
__global__ __launch_bounds__(256, 2) void k_low(
    const float* __restrict__ inr, const float* __restrict__ ini,
    const float* __restrict__ ur, const float* __restrict__ ui,
    float2* __restrict__ outI, float* __restrict__ outR, float* __restrict__ outJ) {
    __shared__ float2 buf[8192];  // 64 KB exactly
    const int t = threadIdx.x;
    const long long base = (long long)blockIdx.y * DIM_ + (long long)blockIdx.x * 8192;

    float2 v[32];
    // load: reg m = k*4+j  <->  l = (k<<10) | (t<<2) | j    (1 KB contiguous per float4 instr)
#pragma unroll
    for (int k = 0; k < 8; ++k) {
        const int l0 = (k << 10) | (t << 2);
        const float4 re = *(const float4*)(inr + base + l0);
        const float4 im = *(const float4*)(ini + base + l0);
        v[k * 4 + 0] = make_float2(re.x, im.x);
        v[k * 4 + 1] = make_float2(re.y, im.y);
        v[k * 4 + 2] = make_float2(re.z, im.z);
        v[k * 4 + 3] = make_float2(re.w, im.w);
    }
    // Phase A: l bit0->m bit0 (q22), bit1->m1 (q21), bit10->m2 (q12), bit11->m3 (q11), bit12->m4 (q10)
    BFLY_STRIDE(1, 22);
    BFLY_STRIDE(2, 21);
    BFLY_STRIDE(4, 12);
    BFLY_STRIDE(8, 11);
    BFLY_STRIDE(16, 10);
#pragma unroll
    for (int m = 0; m < 32; ++m)
        buf[swz(((m >> 2) << 10) | (t << 2) | (m & 3))] = v[m];
    __syncthreads();
    // Phase B: m = l bits 2..6 ; l = (t&3) | (m<<2) | ((t>>2)<<7)
#pragma unroll
    for (int m = 0; m < 32; ++m)
        v[m] = buf[swz((t & 3) | (m << 2) | ((t >> 2) << 7))];
    BFLY_STRIDE(1, 20);
    BFLY_STRIDE(2, 19);
    BFLY_STRIDE(4, 18);
    BFLY_STRIDE(8, 17);
    BFLY_STRIDE(16, 16);
    // write back to the SAME slots (each slot owned by one thread -> no sync needed here)
#pragma unroll
    for (int m = 0; m < 32; ++m)
        buf[swz((t & 3) | (m << 2) | ((t >> 2) << 7))] = v[m];
    __syncthreads();
    // Phase C: m bits{0,1}=l bits{0,1}, m bits{2..4}=l bits{7..9}
#pragma unroll
    for (int m = 0; m < 32; ++m)
        v[m] = buf[swz((m & 3) | ((t & 31) << 2) | ((m >> 2) << 7) | ((t >> 5) << 10))];
    BFLY_STRIDE(4, 15);
    BFLY_STRIDE(8, 14);
    BFLY_STRIDE(16, 13);
#pragma unroll
    for (int m = 0; m < 32; ++m)
        buf[swz((m & 3) | ((t & 31) << 2) | ((m >> 2) << 7) | ((t >> 5) << 10))] = v[m];
    __syncthreads();
    // linear readout: l = r*256 + t -> per-instr 512 B contiguous stores
#pragma unroll
    for (int r = 0; r < 32; ++r) {
        const int l = (r << 8) | t;
        const float2 val = buf[swz(l)];
        if (INTER) {
            outI[base + l] = val;
        } else {
            outR[base + l] = val.x;
            outJ[base + l] = val.y;
        }
    }
}

// ---------------------------------------------------------------------------
// K2: high 10 statevector bits (gates q = 9..0) + fused overlap dot.
// index = h*8192 + l, h in [0,1024). Block = all h x 8 contiguous l values.
// Loads hit 64 B segments (interleaved float2 intermediate). 5 h-bits in
// registers, LDS remap, 5 more, then stream code1 and accumulate
// overlap_ij = sum conj(c0'_i) * c1_j without materializing c0'.
// ---------------------------------------------------------------------------
template <bool INTER>
__global__ __launch_bounds__(256, 2) void k_high(
    const float2* __restrict__ wsI, const float* __restrict__ wsR, const float* __restrict__ wsJ,
    const float* __restrict__ c1r, const float* __restrict__ c1i,
    const float* __restrict__ ur, const float* __restrict__ ui) {
    __shared__ float2 buf[8192];  // 64 KB; reused as reduction scratch at the end
    const int t = threadIdx.x;
    const int l0 = blockIdx.x << 3;  // 1024 blocks x 8 l-values
    float acc[8] = {0.f, 0.f, 0.f, 0.f, 0.f, 0.f, 0.f, 0.f};

    for (int i = 0; i < 2; ++i) {
        const long long ibase = (long long)i * DIM_;
        float2 v[32];
        // load: reg m = h bits 0..4 ; thread t = (h bits 5..9)*8 + l_idx
#pragma unroll
        for (int m = 0; m < 32; ++m) {
            const int h = m | ((t >> 3) << 5);
            const long long idx = ibase + ((long long)h << 13) + l0 + (t & 7);
            if (INTER) v[m] = wsI[idx];
            else       v[m] = make_float2(wsR[idx], wsJ[idx]);
        }
        // h bit b = statevector bit 13+b -> gate q = 9-b
        BFLY_STRIDE(1, 9);
        BFLY_STRIDE(2, 8);
        BFLY_STRIDE(4, 7);
        BFLY_STRIDE(8, 6);
        BFLY_STRIDE(16, 5);
#pragma unroll
        for (int m = 0; m < 32; ++m) {
            const int h = m | ((t >> 3) << 5);
            buf[swz((h << 3) | (t & 7))] = v[m];
        }
        __syncthreads();
        // remap: reg m = h bits 5..9 ; thread t = (h bits 0..4)*8 + l_idx
#pragma unroll
        for (int m = 0; m < 32; ++m) {
            const int h = (t >> 3) | (m << 5);
            v[m] = buf[swz((h << 3) | (t & 7))];
        }
        BFLY_STRIDE(1, 4);
        BFLY_STRIDE(2, 3);
        BFLY_STRIDE(4, 2);
        BFLY_STRIDE(8, 1);
        BFLY_STRIDE(16, 0);
        // fused partial dots: acc[i*4+{0,1,2,3}] = {Re,Im}x{j=0,j=1}
#pragma unroll
        for (int m = 0; m < 32; ++m) {
            const int h = (t >> 3) | (m << 5);
            const long long idx = ((long long)h << 13) + l0 + (t & 7);
            const float ar = c1r[idx], ai = c1i[idx];
            const float br = c1r[DIM_ + idx], bi = c1i[DIM_ + idx];
            acc[i * 4 + 0] += v[m].x * ar + v[m].y * ai;
            acc[i * 4 + 1] += v[m].x * ai - v[m].y * ar;
            acc[i * 4 + 2] += v[m].x * br + v[m].y * bi;
            acc[i * 4 + 3] += v[m].x * bi - v[m].y * br;
        }
        __syncthreads();  // buf reused by next i / by reduction
    }
    // wave reduce (64-lane), then cross-wave via LDS, then one atomic per block
#pragma unroll
    for (int k = 0; k < 8; ++k)
#pragma unroll
        for (int off = 32; off > 0; off >>= 1)
            acc[k] += __shfl_down(acc[k], off, 64);
    float* red = (float*)buf;
    const int wave = t >> 6, lane = t & 63;
    if (lane == 0) {
#pragma unroll
        for (int k = 0; k < 8; ++k) red[wave * 8 + k] = acc[k];
    }
    __syncthreads();
    if (t < 8) atomicAdd(&g_acc[t], red[t] + red[8 + t] + red[16 + t] + red[24 + t]);
}

__global__ void k_zero() {
    if (threadIdx.x < 8) g_acc[threadIdx.x] = 0.f;
}

__global__ void k_fin(float* __restrict__ out) {
    if (threadIdx.x == 0) {
        float s = 0.f;
#pragma unroll
        for (int k = 0; k < 4; ++k)
            s += g_acc[2 * k] * g_acc[2 * k] + g_acc[2 * k + 1] * g_acc[2 * k + 1];
        out[0] = (float)N0_ - s;
    }
}

extern "C" void kernel_launch(void* const* d_in, const int* in_sizes, int n_in,
                              void* d_out, int out_size, void* d_ws, size_t ws_size,
                              hipStream_t stream) {
    const float* c0r = (const float*)d_in[0];
    const float* c0i = (const float*)d_in[1];
    const float* c1r = (const float*)d_in[2];
    const float* c1i = (const float*)d_in[3];
    const float* ur  = (const float*)d_in[4];
    const float* ui  = (const float*)d_in[5];
    float* out = (float*)d_out;

    const size_t need = (size_t)N0_ * DIM_ * sizeof(float2);  // 128 MB intermediate
    k_zero<<<1, 64, 0, stream>>>();
    dim3 g1(1024, N0_);
    if (d_ws != nullptr && ws_size >= need) {
        float2* wsI = (float2*)d_ws;
        k_low<true><<<g1, 256, 0, stream>>>(c0r, c0i, ur, ui, wsI, nullptr, nullptr);
        k_high<true><<<1024, 256, 0, stream>>>(wsI, nullptr, nullptr, c1r, c1i, ur, ui);
    } else {
        // fallback: write intermediate in place into code0 planes (harness
        // restores d_in from pristine copies before every timed launch)
        float* oR = (float*)c0r;
        float* oJ = (float*)c0i;
        k_low<false><<<g1, 256, 0, stream>>>(c0r, c0i, ur, ui, nullptr, oR, oJ);
        k_high<false><<<1024, 256, 0, stream>>>(nullptr, oR, oJ, c1r, c1i, ur, ui);
    }
    k_fin<<<1, 64, 0, stream>>>(out);
}